// Round 1
// baseline (1378.442 us; speedup 1.0000x reference)
//
#include <hip/hip_runtime.h>
#include <cmath>

#define N      50000
#define E      800000
#define NFEAT  128
#define NHID   128
#define NCLASS 40
#define NUM_HOPS 4
#define NF     (N * NHID)   // 6,400,000 floats per h buffer

// ---------------- CSR build ----------------

__global__ void k_hist(const int* __restrict__ row, int* __restrict__ cnt) {
    int e = blockIdx.x * blockDim.x + threadIdx.x;
    if (e < E) atomicAdd(&cnt[row[e]], 1);
}

// Single-block exclusive scan over cnt[0..N-1] -> rp[0..N]
__global__ void k_scan(const int* __restrict__ cnt, int* __restrict__ rp) {
    __shared__ int ss[1024];
    int t = threadIdx.x;
    const int CH = (N + 1023) / 1024;
    int beg = t * CH; if (beg > N) beg = N;
    int end = beg + CH; if (end > N) end = N;
    int s = 0;
    for (int i = beg; i < end; ++i) s += cnt[i];
    ss[t] = s;
    __syncthreads();
    if (t == 0) {
        int run = 0;
        for (int i = 0; i < 1024; ++i) { int v = ss[i]; ss[i] = run; run += v; }
    }
    __syncthreads();
    int run = ss[t];
    for (int i = beg; i < end; ++i) { rp[i] = run; run += cnt[i]; }
    if (end == N) rp[N] = run;   // several threads write E; benign
}

__global__ void k_scatter(const int* __restrict__ row, const int* __restrict__ col,
                          const float* __restrict__ val,
                          int* __restrict__ cur, int* __restrict__ cs, float* __restrict__ vs) {
    int e = blockIdx.x * blockDim.x + threadIdx.x;
    if (e < E) {
        int r = row[e];
        int p = atomicAdd(&cur[r], 1);
        cs[p] = col[e];
        vs[p] = val[e];
    }
}

// ---------------- SpMM: y[row] = sum_j val_j * x[col_j]  (one wave per row) ----------------

__global__ void k_spmm(const int* __restrict__ rp, const int* __restrict__ cs,
                       const float* __restrict__ vs,
                       const float* __restrict__ x, float* __restrict__ y) {
    int wid  = (blockIdx.x * blockDim.x + threadIdx.x) >> 6;   // global wave id = row
    if (wid >= N) return;
    int lane = threadIdx.x & 63;
    int beg = rp[wid], end = rp[wid + 1];
    float ax = 0.f, ay = 0.f;
    for (int j = beg; j < end; ++j) {
        int   c = cs[j];
        float v = vs[j];
        const float2 xv = ((const float2*)(x + c * NHID))[lane];
        ax = fmaf(v, xv.x, ax);
        ay = fmaf(v, xv.y, ay);
    }
    float2 o; o.x = ax; o.y = ay;
    ((float2*)(y + wid * NHID))[lane] = o;
}

// ---------------- GEMM (128x128 W) + ReLU: block = 2 rows x 128 cols ----------------

__global__ void k_gemm_relu(const float* __restrict__ x, const float* __restrict__ W,
                            float* __restrict__ y) {
    int col = threadIdx.x & 127;
    int row = (blockIdx.x << 1) + (threadIdx.x >> 7);
    if (row >= N) return;
    const float* xr = x + row * NHID;
    float acc = 0.f;
#pragma unroll 8
    for (int k = 0; k < NHID; ++k)
        acc = fmaf(xr[k], W[k * NHID + col], acc);
    y[row * NHID + col] = fmaxf(acc, 0.f);
}

// ---------------- Scores: sigmoid(h_i . w_h + f . w_f + b) -> softmax over hops ----------------

__global__ void k_scores(const float* __restrict__ f, const float* __restrict__ hb,
                         const float* __restrict__ att_w, const float* __restrict__ att_b,
                         float* __restrict__ Wsm) {
    int node = (blockIdx.x * blockDim.x + threadIdx.x) >> 6;
    if (node >= N) return;
    int lane = threadIdx.x & 63;
    const float2 whv = ((const float2*)att_w)[lane];
    const float2 wfv = ((const float2*)(att_w + NHID))[lane];
    const float2 fv  = ((const float2*)(f + node * NFEAT))[lane];
    float s4 = fv.x * wfv.x + fv.y * wfv.y;
    float s0, s1, s2, s3;
    {
        const float2 h0 = ((const float2*)(hb + 0 * (size_t)NF + node * NHID))[lane];
        const float2 h1 = ((const float2*)(hb + 1 * (size_t)NF + node * NHID))[lane];
        const float2 h2 = ((const float2*)(hb + 2 * (size_t)NF + node * NHID))[lane];
        const float2 h3 = ((const float2*)(hb + 3 * (size_t)NF + node * NHID))[lane];
        s0 = h0.x * whv.x + h0.y * whv.y;
        s1 = h1.x * whv.x + h1.y * whv.y;
        s2 = h2.x * whv.x + h2.y * whv.y;
        s3 = h3.x * whv.x + h3.y * whv.y;
    }
    for (int off = 32; off; off >>= 1) {
        s0 += __shfl_down(s0, off);
        s1 += __shfl_down(s1, off);
        s2 += __shfl_down(s2, off);
        s3 += __shfl_down(s3, off);
        s4 += __shfl_down(s4, off);
    }
    if (lane == 0) {
        float b = att_b[0];
        float g0 = 1.f / (1.f + __expf(-(s0 + s4 + b)));
        float g1 = 1.f / (1.f + __expf(-(s1 + s4 + b)));
        float g2 = 1.f / (1.f + __expf(-(s2 + s4 + b)));
        float g3 = 1.f / (1.f + __expf(-(s3 + s4 + b)));
        float m = fmaxf(fmaxf(g0, g1), fmaxf(g2, g3));
        float e0 = __expf(g0 - m), e1 = __expf(g1 - m), e2 = __expf(g2 - m), e3 = __expf(g3 - m);
        float inv = 1.f / (e0 + e1 + e2 + e3);
        Wsm[0 * N + node] = e0 * inv;
        Wsm[1 * N + node] = e1 * inv;
        Wsm[2 * N + node] = e2 * inv;
        Wsm[3 * N + node] = e3 * inv;
    }
}

// ---------------- Final: weighted hop sum -> fc -> log_softmax (one wave per node) ----------------

__global__ void k_final(const float* __restrict__ hb, const float* __restrict__ Wsm,
                        const float* __restrict__ fc_w, const float* __restrict__ fc_b,
                        float* __restrict__ out) {
    __shared__ float xs[4][NHID];
    int wslot = threadIdx.x >> 6;
    int node  = blockIdx.x * 4 + wslot;
    int lane  = threadIdx.x & 63;
    if (node < N) {
        float w0 = Wsm[0 * N + node], w1 = Wsm[1 * N + node];
        float w2 = Wsm[2 * N + node], w3 = Wsm[3 * N + node];
        const float2 h0 = ((const float2*)(hb + 0 * (size_t)NF + node * NHID))[lane];
        const float2 h1 = ((const float2*)(hb + 1 * (size_t)NF + node * NHID))[lane];
        const float2 h2 = ((const float2*)(hb + 2 * (size_t)NF + node * NHID))[lane];
        const float2 h3 = ((const float2*)(hb + 3 * (size_t)NF + node * NHID))[lane];
        float ax = w0 * h0.x + w1 * h1.x + w2 * h2.x + w3 * h3.x;
        float ay = w0 * h0.y + w1 * h1.y + w2 * h2.y + w3 * h3.y;
        xs[wslot][2 * lane]     = ax;
        xs[wslot][2 * lane + 1] = ay;
    }
    __syncthreads();
    if (node < N) {
        float logit = 0.f;
        if (lane < NCLASS) {
            logit = fc_b[lane];
#pragma unroll 8
            for (int k = 0; k < NHID; ++k)
                logit = fmaf(xs[wslot][k], fc_w[k * NCLASS + lane], logit);
        }
        float mv = (lane < NCLASS) ? logit : -INFINITY;
        for (int off = 32; off; off >>= 1) mv = fmaxf(mv, __shfl_xor(mv, off));
        float ev = (lane < NCLASS) ? __expf(logit - mv) : 0.f;
        float sum = ev;
        for (int off = 32; off; off >>= 1) sum += __shfl_xor(sum, off);
        if (lane < NCLASS)
            out[node * NCLASS + lane] = logit - mv - logf(sum);
    }
}

// ---------------- launch ----------------

extern "C" void kernel_launch(void* const* d_in, const int* in_sizes, int n_in,
                              void* d_out, int out_size, void* d_ws, size_t ws_size,
                              hipStream_t stream) {
    const float* features = (const float*)d_in[0];
    const int*   erow     = (const int*)d_in[1];
    const int*   ecol     = (const int*)d_in[2];
    const float* eval_    = (const float*)d_in[3];
    const float* Wg       = (const float*)d_in[4];
    const float* att_w    = (const float*)d_in[5];
    const float* att_b    = (const float*)d_in[6];
    const float* fc_w     = (const float*)d_in[7];
    const float* fc_b     = (const float*)d_in[8];
    float*       out      = (float*)d_out;

    // workspace layout (all float-size elements; ~136 MB total)
    float* hb  = (float*)d_ws;                 // 4*NF   : h1..h4
    float* tmp = hb + 4 * (size_t)NF;          // NF     : spmm result
    float* vs  = tmp + NF;                     // E      : sorted edge vals
    float* Wsm = vs + E;                       // 4*N    : softmax hop weights
    int*   rp  = (int*)(Wsm + 4 * N);          // N+1 (+pad)
    int*   cnt = rp + (N + 4);                 // N      : histogram / cursor
    int*   cs  = cnt + N;                      // E      : sorted edge cols

    // CSR build
    hipMemsetAsync(cnt, 0, N * sizeof(int), stream);
    k_hist<<<(E + 255) / 256, 256, 0, stream>>>(erow, cnt);
    k_scan<<<1, 1024, 0, stream>>>(cnt, rp);
    hipMemcpyAsync(cnt, rp, N * sizeof(int), hipMemcpyDeviceToDevice, stream);
    k_scatter<<<(E + 255) / 256, 256, 0, stream>>>(erow, ecol, eval_, cnt, cs, vs);

    // hops
    const float* hprev = features;
    for (int i = 0; i < NUM_HOPS; ++i) {
        k_spmm<<<(N * 64 + 255) / 256, 256, 0, stream>>>(rp, cs, vs, hprev, tmp);
        k_gemm_relu<<<(N + 1) / 2, 256, 0, stream>>>(tmp, Wg + (size_t)i * NHID * NHID,
                                                     hb + (size_t)i * NF);
        hprev = hb + (size_t)i * NF;
    }

    // attention scores + softmax over hops
    k_scores<<<(N + 3) / 4, 256, 0, stream>>>(features, hb, att_w, att_b, Wsm);

    // weighted sum -> fc -> log_softmax
    k_final<<<(N + 3) / 4, 256, 0, stream>>>(hb, Wsm, fc_w, fc_b, out);
}

// Round 2
// 880.818 us; speedup vs baseline: 1.5650x; 1.5650x over previous
//
#include <hip/hip_runtime.h>
#include <cmath>

#define N      50000
#define E      800000
#define NFEAT  128
#define NHID   128
#define NCLASS 40
#define NUM_HOPS 4
#define NF     (N * NHID)   // 6,400,000 floats per h buffer
#define GR     64           // GEMM rows per block

// ---------------- CSR build ----------------

__global__ void k_hist(const int* __restrict__ row, int* __restrict__ cnt) {
    int e = blockIdx.x * blockDim.x + threadIdx.x;
    if (e < E) atomicAdd(&cnt[row[e]], 1);
}

// Single-block exclusive scan over cnt[0..N-1] -> rp[0..N] (two-level shuffle scan)
__global__ void k_scan(const int* __restrict__ cnt, int* __restrict__ rp) {
    __shared__ int ws[16];
    int t = threadIdx.x;
    const int CH = (N + 1023) / 1024;
    int beg = t * CH; if (beg > N) beg = N;
    int end = beg + CH; if (end > N) end = N;
    int s = 0;
    for (int i = beg; i < end; ++i) s += cnt[i];
    int lane = t & 63, w = t >> 6;
    // inclusive scan within wave
    int v = s;
    for (int off = 1; off < 64; off <<= 1) {
        int u = __shfl_up(v, off);
        if (lane >= off) v += u;
    }
    if (lane == 63) ws[w] = v;
    __syncthreads();
    if (t < 16) {
        int u = ws[t];
        for (int off = 1; off < 16; off <<= 1) {
            int q = __shfl_up(u, off);
            if (t >= off) u += q;
        }
        ws[t] = u;
    }
    __syncthreads();
    int excl = v - s + (w ? ws[w - 1] : 0);
    int run = excl;
    for (int i = beg; i < end; ++i) { rp[i] = run; run += cnt[i]; }
    if (end == N) rp[N] = run;   // several threads write E; benign
}

__global__ void k_scatter(const int* __restrict__ row, const int* __restrict__ col,
                          const float* __restrict__ val,
                          int* __restrict__ cur, int2* __restrict__ ev) {
    int e = blockIdx.x * blockDim.x + threadIdx.x;
    if (e < E) {
        int r = row[e];
        int p = atomicAdd(&cur[r], 1);
        ev[p] = make_int2(col[e], __float_as_int(val[e]));
    }
}

// ---------------- SpMM: y[row] = sum_j val_j * x[col_j]  (one wave per row) ----------------

__global__ void k_spmm(const int* __restrict__ rp, const int2* __restrict__ ev,
                       const float* __restrict__ x, float* __restrict__ y) {
    int wid  = (blockIdx.x * blockDim.x + threadIdx.x) >> 6;   // global wave id = row
    if (wid >= N) return;
    int lane = threadIdx.x & 63;
    int beg = rp[wid], end = rp[wid + 1];
    float ax = 0.f, ay = 0.f;
    if (beg < end) {
        int2 e = ev[beg];
        for (int j = beg; j < end; ++j) {
            int2 en = (j + 1 < end) ? ev[j + 1] : e;   // prefetch (independent of gather)
            const float2 xv = ((const float2*)(x + (size_t)e.x * NHID))[lane];
            float v = __int_as_float(e.y);
            ax = fmaf(v, xv.x, ax);
            ay = fmaf(v, xv.y, ay);
            e = en;
        }
    }
    float2 o; o.x = ax; o.y = ay;
    ((float2*)(y + (size_t)wid * NHID))[lane] = o;
}

// ---------------- GEMM (128x128 W) + ReLU ----------------
// 64 rows/block, 256 threads, thread tile 8 rows x 4 cols (32 accumulators).
// x tile staged in LDS (32 KB); W streamed float4 with k+1 prefetch (L2-hot).

__global__ __launch_bounds__(256) void k_gemm_relu(const float* __restrict__ x,
                                                   const float* __restrict__ W,
                                                   float* __restrict__ y) {
    __shared__ float xl[GR * NHID];
    int t = threadIdx.x;
    int rowbase = blockIdx.x * GR;
    int nrows = N - rowbase; if (nrows > GR) nrows = GR;
    {
        float4* xl4 = (float4*)xl;
        const float4* xg4 = (const float4*)(x + (size_t)rowbase * NHID);
        int maxq = nrows * (NHID / 4);
#pragma unroll
        for (int i = 0; i < (GR * NHID / 4) / 256; ++i) {   // 8 iters
            int idx = i * 256 + t;
            if (idx < maxq) xl4[idx] = xg4[idx];
        }
    }
    __syncthreads();
    int cg = (t & 31) << 2;   // col base (4 cols)
    int rg = (t >> 5) << 3;   // row base (8 rows)
    float4 acc[8];
#pragma unroll
    for (int r = 0; r < 8; ++r) acc[r] = make_float4(0.f, 0.f, 0.f, 0.f);
    const float4* Wq = (const float4*)W;
    float4 w = Wq[cg >> 2];
    for (int k = 0; k < NHID; ++k) {
        float4 wn = (k + 1 < NHID) ? Wq[(k + 1) * (NHID / 4) + (cg >> 2)] : w;
#pragma unroll
        for (int r = 0; r < 8; ++r) {
            float xv = xl[(rg + r) * NHID + k];   // wave-uniform -> LDS broadcast
            acc[r].x = fmaf(xv, w.x, acc[r].x);
            acc[r].y = fmaf(xv, w.y, acc[r].y);
            acc[r].z = fmaf(xv, w.z, acc[r].z);
            acc[r].w = fmaf(xv, w.w, acc[r].w);
        }
        w = wn;
    }
#pragma unroll
    for (int r = 0; r < 8; ++r) {
        int row = rowbase + rg + r;
        if (row < N) {
            float4 o;
            o.x = fmaxf(acc[r].x, 0.f);
            o.y = fmaxf(acc[r].y, 0.f);
            o.z = fmaxf(acc[r].z, 0.f);
            o.w = fmaxf(acc[r].w, 0.f);
            *(float4*)(y + (size_t)row * NHID + cg) = o;
        }
    }
}

// ---------------- Scores: sigmoid(h_i . w_h + f . w_f + b) -> softmax over hops ----------------

__global__ void k_scores(const float* __restrict__ f, const float* __restrict__ hb,
                         const float* __restrict__ att_w, const float* __restrict__ att_b,
                         float* __restrict__ Wsm) {
    int node = (blockIdx.x * blockDim.x + threadIdx.x) >> 6;
    if (node >= N) return;
    int lane = threadIdx.x & 63;
    const float2 whv = ((const float2*)att_w)[lane];
    const float2 wfv = ((const float2*)(att_w + NHID))[lane];
    const float2 fv  = ((const float2*)(f + (size_t)node * NFEAT))[lane];
    float s4 = fv.x * wfv.x + fv.y * wfv.y;
    float s0, s1, s2, s3;
    {
        const float2 h0 = ((const float2*)(hb + 0 * (size_t)NF + (size_t)node * NHID))[lane];
        const float2 h1 = ((const float2*)(hb + 1 * (size_t)NF + (size_t)node * NHID))[lane];
        const float2 h2 = ((const float2*)(hb + 2 * (size_t)NF + (size_t)node * NHID))[lane];
        const float2 h3 = ((const float2*)(hb + 3 * (size_t)NF + (size_t)node * NHID))[lane];
        s0 = h0.x * whv.x + h0.y * whv.y;
        s1 = h1.x * whv.x + h1.y * whv.y;
        s2 = h2.x * whv.x + h2.y * whv.y;
        s3 = h3.x * whv.x + h3.y * whv.y;
    }
    for (int off = 32; off; off >>= 1) {
        s0 += __shfl_down(s0, off);
        s1 += __shfl_down(s1, off);
        s2 += __shfl_down(s2, off);
        s3 += __shfl_down(s3, off);
        s4 += __shfl_down(s4, off);
    }
    if (lane == 0) {
        float b = att_b[0];
        float g0 = 1.f / (1.f + __expf(-(s0 + s4 + b)));
        float g1 = 1.f / (1.f + __expf(-(s1 + s4 + b)));
        float g2 = 1.f / (1.f + __expf(-(s2 + s4 + b)));
        float g3 = 1.f / (1.f + __expf(-(s3 + s4 + b)));
        float m = fmaxf(fmaxf(g0, g1), fmaxf(g2, g3));
        float e0 = __expf(g0 - m), e1 = __expf(g1 - m), e2 = __expf(g2 - m), e3 = __expf(g3 - m);
        float inv = 1.f / (e0 + e1 + e2 + e3);
        Wsm[0 * N + node] = e0 * inv;
        Wsm[1 * N + node] = e1 * inv;
        Wsm[2 * N + node] = e2 * inv;
        Wsm[3 * N + node] = e3 * inv;
    }
}

// ---------------- Final: weighted hop sum -> fc -> log_softmax (one wave per node) ----------------

__global__ void k_final(const float* __restrict__ hb, const float* __restrict__ Wsm,
                        const float* __restrict__ fc_w, const float* __restrict__ fc_b,
                        float* __restrict__ out) {
    __shared__ float xs[4][NHID];
    int wslot = threadIdx.x >> 6;
    int node  = blockIdx.x * 4 + wslot;
    int lane  = threadIdx.x & 63;
    if (node < N) {
        float w0 = Wsm[0 * N + node], w1 = Wsm[1 * N + node];
        float w2 = Wsm[2 * N + node], w3 = Wsm[3 * N + node];
        const float2 h0 = ((const float2*)(hb + 0 * (size_t)NF + (size_t)node * NHID))[lane];
        const float2 h1 = ((const float2*)(hb + 1 * (size_t)NF + (size_t)node * NHID))[lane];
        const float2 h2 = ((const float2*)(hb + 2 * (size_t)NF + (size_t)node * NHID))[lane];
        const float2 h3 = ((const float2*)(hb + 3 * (size_t)NF + (size_t)node * NHID))[lane];
        float ax = w0 * h0.x + w1 * h1.x + w2 * h2.x + w3 * h3.x;
        float ay = w0 * h0.y + w1 * h1.y + w2 * h2.y + w3 * h3.y;
        xs[wslot][2 * lane]     = ax;
        xs[wslot][2 * lane + 1] = ay;
    }
    __syncthreads();
    if (node < N) {
        float logit = 0.f;
        if (lane < NCLASS) {
            logit = fc_b[lane];
#pragma unroll 8
            for (int k = 0; k < NHID; ++k)
                logit = fmaf(xs[wslot][k], fc_w[k * NCLASS + lane], logit);
        }
        float mv = (lane < NCLASS) ? logit : -INFINITY;
        for (int off = 32; off; off >>= 1) mv = fmaxf(mv, __shfl_xor(mv, off));
        float ev = (lane < NCLASS) ? __expf(logit - mv) : 0.f;
        float sum = ev;
        for (int off = 32; off; off >>= 1) sum += __shfl_xor(sum, off);
        if (lane < NCLASS)
            out[(size_t)node * NCLASS + lane] = logit - mv - logf(sum);
    }
}

// ---------------- launch ----------------

extern "C" void kernel_launch(void* const* d_in, const int* in_sizes, int n_in,
                              void* d_out, int out_size, void* d_ws, size_t ws_size,
                              hipStream_t stream) {
    const float* features = (const float*)d_in[0];
    const int*   erow     = (const int*)d_in[1];
    const int*   ecol     = (const int*)d_in[2];
    const float* eval_    = (const float*)d_in[3];
    const float* Wg       = (const float*)d_in[4];
    const float* att_w    = (const float*)d_in[5];
    const float* att_b    = (const float*)d_in[6];
    const float* fc_w     = (const float*)d_in[7];
    const float* fc_b     = (const float*)d_in[8];
    float*       out      = (float*)d_out;

    // workspace layout (float-size slots; ~136 MB total)
    float* hb  = (float*)d_ws;                 // 4*NF   : h1..h4
    float* tmp = hb + 4 * (size_t)NF;          // NF     : spmm result
    int2*  ev  = (int2*)(tmp + NF);            // E int2 : packed (col, val)
    float* Wsm = (float*)(ev + E);             // 4*N    : softmax hop weights
    int*   rp  = (int*)(Wsm + 4 * N);          // N+1 (+pad)
    int*   cnt = rp + (N + 4);                 // N      : histogram / cursor

    // CSR build
    hipMemsetAsync(cnt, 0, N * sizeof(int), stream);
    k_hist<<<(E + 255) / 256, 256, 0, stream>>>(erow, cnt);
    k_scan<<<1, 1024, 0, stream>>>(cnt, rp);
    hipMemcpyAsync(cnt, rp, N * sizeof(int), hipMemcpyDeviceToDevice, stream);
    k_scatter<<<(E + 255) / 256, 256, 0, stream>>>(erow, ecol, eval_, cnt, ev);

    // hops
    const float* hprev = features;
    for (int i = 0; i < NUM_HOPS; ++i) {
        k_spmm<<<(N * 64 + 255) / 256, 256, 0, stream>>>(rp, ev, hprev, tmp);
        k_gemm_relu<<<(N + GR - 1) / GR, 256, 0, stream>>>(tmp, Wg + (size_t)i * NHID * NHID,
                                                           hb + (size_t)i * NF);
        hprev = hb + (size_t)i * NF;
    }

    // attention scores + softmax over hops
    k_scores<<<(N + 3) / 4, 256, 0, stream>>>(features, hb, att_w, att_b, Wsm);

    // weighted sum -> fc -> log_softmax
    k_final<<<(N + 3) / 4, 256, 0, stream>>>(hb, Wsm, fc_w, fc_b, out);
}

// Round 3
// 701.049 us; speedup vs baseline: 1.9663x; 1.2564x over previous
//
#include <hip/hip_runtime.h>
#include <cmath>

#define N      50000
#define E      800000
#define NFEAT  128
#define NHID   128
#define NCLASS 40
#define NUM_HOPS 4
#define NF     (N * NHID)   // 6,400,000 floats per h buffer
#define GR     64           // GEMM rows per block

// ---------------- CSR build ----------------

__global__ void k_hist(const int* __restrict__ row, int* __restrict__ cnt) {
    int e = blockIdx.x * blockDim.x + threadIdx.x;
    if (e < E) atomicAdd(&cnt[row[e]], 1);
}

// Single-block exclusive scan over cnt[0..N-1] -> rp[0..N]; also rewrites cnt = rp
// (scatter cursor) so no d2d copy is needed.
__global__ void k_scan(int* __restrict__ cnt, int* __restrict__ rp) {
    __shared__ int ws[16];
    int t = threadIdx.x;
    const int CH = (N + 1023) / 1024;
    int beg = t * CH; if (beg > N) beg = N;
    int end = beg + CH; if (end > N) end = N;
    int s = 0;
    for (int i = beg; i < end; ++i) s += cnt[i];
    int lane = t & 63, w = t >> 6;
    int v = s;
    for (int off = 1; off < 64; off <<= 1) {
        int u = __shfl_up(v, off);
        if (lane >= off) v += u;
    }
    if (lane == 63) ws[w] = v;
    __syncthreads();
    if (t < 16) {
        int u = ws[t];
        for (int off = 1; off < 16; off <<= 1) {
            int q = __shfl_up(u, off);
            if (t >= off) u += q;
        }
        ws[t] = u;
    }
    __syncthreads();
    int run = v - s + (w ? ws[w - 1] : 0);   // exclusive prefix
    for (int i = beg; i < end; ++i) {
        int c = cnt[i];
        rp[i]  = run;
        cnt[i] = run;   // scatter cursor
        run += c;
    }
    if (end == N) rp[N] = run;   // several threads write E; benign
}

__global__ void k_scatter(const int* __restrict__ row, const int* __restrict__ col,
                          const float* __restrict__ val,
                          int* __restrict__ cur, int2* __restrict__ ev) {
    int e = blockIdx.x * blockDim.x + threadIdx.x;
    if (e < E) {
        int r = row[e];
        int p = atomicAdd(&cur[r], 1);
        ev[p] = make_int2(col[e], __float_as_int(val[e]));
    }
}

// ---------------- SpMM: y[row] = sum_j val_j * x[col_j]  (one wave per row) ----------------
// Edge-unrolled x4: 4 independent 512 B row-gathers in flight per wave (MLP).
// FMA chain preserves strict sequential edge order -> bit-identical to scalar loop.

__global__ void k_spmm(const int* __restrict__ rp, const int2* __restrict__ ev,
                       const float* __restrict__ x, float* __restrict__ y) {
    int wid  = (blockIdx.x * blockDim.x + threadIdx.x) >> 6;   // global wave id = row
    if (wid >= N) return;
    int lane = threadIdx.x & 63;
    int beg = rp[wid], end = rp[wid + 1];
    float ax = 0.f, ay = 0.f;
    int j = beg;
    for (; j + 4 <= end; j += 4) {
        int2 e0 = ev[j], e1 = ev[j + 1], e2 = ev[j + 2], e3 = ev[j + 3];
        float2 x0 = ((const float2*)(x + (size_t)e0.x * NHID))[lane];
        float2 x1 = ((const float2*)(x + (size_t)e1.x * NHID))[lane];
        float2 x2 = ((const float2*)(x + (size_t)e2.x * NHID))[lane];
        float2 x3 = ((const float2*)(x + (size_t)e3.x * NHID))[lane];
        float v0 = __int_as_float(e0.y), v1 = __int_as_float(e1.y);
        float v2 = __int_as_float(e2.y), v3 = __int_as_float(e3.y);
        ax = fmaf(v0, x0.x, ax); ay = fmaf(v0, x0.y, ay);
        ax = fmaf(v1, x1.x, ax); ay = fmaf(v1, x1.y, ay);
        ax = fmaf(v2, x2.x, ax); ay = fmaf(v2, x2.y, ay);
        ax = fmaf(v3, x3.x, ax); ay = fmaf(v3, x3.y, ay);
    }
    for (; j < end; ++j) {
        int2 e = ev[j];
        const float2 xv = ((const float2*)(x + (size_t)e.x * NHID))[lane];
        float v = __int_as_float(e.y);
        ax = fmaf(v, xv.x, ax);
        ay = fmaf(v, xv.y, ay);
    }
    float2 o; o.x = ax; o.y = ay;
    ((float2*)(y + (size_t)wid * NHID))[lane] = o;
}

// ---------------- GEMM (128x128 W) + ReLU ----------------
// 64 rows/block, 256 threads, thread tile 8 rows x 4 cols (32 accumulators).
// x tile staged in LDS (32 KB); W streamed float4 with k+1 prefetch (L2-hot).

__global__ __launch_bounds__(256) void k_gemm_relu(const float* __restrict__ x,
                                                   const float* __restrict__ W,
                                                   float* __restrict__ y) {
    __shared__ float xl[GR * NHID];
    int t = threadIdx.x;
    int rowbase = blockIdx.x * GR;
    int nrows = N - rowbase; if (nrows > GR) nrows = GR;
    {
        float4* xl4 = (float4*)xl;
        const float4* xg4 = (const float4*)(x + (size_t)rowbase * NHID);
        int maxq = nrows * (NHID / 4);
#pragma unroll
        for (int i = 0; i < (GR * NHID / 4) / 256; ++i) {   // 8 iters
            int idx = i * 256 + t;
            if (idx < maxq) xl4[idx] = xg4[idx];
        }
    }
    __syncthreads();
    int cg = (t & 31) << 2;   // col base (4 cols)
    int rg = (t >> 5) << 3;   // row base (8 rows)
    float4 acc[8];
#pragma unroll
    for (int r = 0; r < 8; ++r) acc[r] = make_float4(0.f, 0.f, 0.f, 0.f);
    const float4* Wq = (const float4*)W;
    float4 w = Wq[cg >> 2];
    for (int k = 0; k < NHID; ++k) {
        float4 wn = (k + 1 < NHID) ? Wq[(k + 1) * (NHID / 4) + (cg >> 2)] : w;
#pragma unroll
        for (int r = 0; r < 8; ++r) {
            float xv = xl[(rg + r) * NHID + k];   // wave-uniform per half-wave -> LDS broadcast
            acc[r].x = fmaf(xv, w.x, acc[r].x);
            acc[r].y = fmaf(xv, w.y, acc[r].y);
            acc[r].z = fmaf(xv, w.z, acc[r].z);
            acc[r].w = fmaf(xv, w.w, acc[r].w);
        }
        w = wn;
    }
#pragma unroll
    for (int r = 0; r < 8; ++r) {
        int row = rowbase + rg + r;
        if (row < N) {
            float4 o;
            o.x = fmaxf(acc[r].x, 0.f);
            o.y = fmaxf(acc[r].y, 0.f);
            o.z = fmaxf(acc[r].z, 0.f);
            o.w = fmaxf(acc[r].w, 0.f);
            *(float4*)(y + (size_t)row * NHID + cg) = o;
        }
    }
}

// ---------------- Fused attention + output head (one wave per node) ----------------
// scores -> sigmoid -> hop-softmax -> weighted hop sum -> fc -> log_softmax.
// Single pass over hb (reads each h exactly once here).

__global__ void k_attn_final(const float* __restrict__ f, const float* __restrict__ hb,
                             const float* __restrict__ att_w, const float* __restrict__ att_b,
                             const float* __restrict__ fc_w, const float* __restrict__ fc_b,
                             float* __restrict__ out) {
    __shared__ float xs[4][NHID];
    int wslot = threadIdx.x >> 6;
    int node  = blockIdx.x * 4 + wslot;
    int lane  = threadIdx.x & 63;
    if (node < N) {
        const float2 whv = ((const float2*)att_w)[lane];
        const float2 wfv = ((const float2*)(att_w + NHID))[lane];
        const float2 fv  = ((const float2*)(f + (size_t)node * NFEAT))[lane];
        const float2 h0 = ((const float2*)(hb + 0 * (size_t)NF + (size_t)node * NHID))[lane];
        const float2 h1 = ((const float2*)(hb + 1 * (size_t)NF + (size_t)node * NHID))[lane];
        const float2 h2 = ((const float2*)(hb + 2 * (size_t)NF + (size_t)node * NHID))[lane];
        const float2 h3 = ((const float2*)(hb + 3 * (size_t)NF + (size_t)node * NHID))[lane];
        float s0 = h0.x * whv.x + h0.y * whv.y;
        float s1 = h1.x * whv.x + h1.y * whv.y;
        float s2 = h2.x * whv.x + h2.y * whv.y;
        float s3 = h3.x * whv.x + h3.y * whv.y;
        float s4 = fv.x * wfv.x + fv.y * wfv.y;
        for (int off = 32; off; off >>= 1) {   // butterfly: every lane gets the sums
            s0 += __shfl_xor(s0, off);
            s1 += __shfl_xor(s1, off);
            s2 += __shfl_xor(s2, off);
            s3 += __shfl_xor(s3, off);
            s4 += __shfl_xor(s4, off);
        }
        float b = att_b[0];
        float g0 = 1.f / (1.f + __expf(-(s0 + s4 + b)));
        float g1 = 1.f / (1.f + __expf(-(s1 + s4 + b)));
        float g2 = 1.f / (1.f + __expf(-(s2 + s4 + b)));
        float g3 = 1.f / (1.f + __expf(-(s3 + s4 + b)));
        float m = fmaxf(fmaxf(g0, g1), fmaxf(g2, g3));
        float e0 = __expf(g0 - m), e1 = __expf(g1 - m), e2 = __expf(g2 - m), e3 = __expf(g3 - m);
        float inv = 1.f / (e0 + e1 + e2 + e3);
        float w0 = e0 * inv, w1 = e1 * inv, w2 = e2 * inv, w3 = e3 * inv;
        float ax = w0 * h0.x + w1 * h1.x + w2 * h2.x + w3 * h3.x;
        float ay = w0 * h0.y + w1 * h1.y + w2 * h2.y + w3 * h3.y;
        xs[wslot][2 * lane]     = ax;
        xs[wslot][2 * lane + 1] = ay;
    }
    __syncthreads();
    if (node < N) {
        float logit = 0.f;
        if (lane < NCLASS) {
            logit = fc_b[lane];
#pragma unroll 8
            for (int k = 0; k < NHID; ++k)
                logit = fmaf(xs[wslot][k], fc_w[k * NCLASS + lane], logit);
        }
        float mv = (lane < NCLASS) ? logit : -INFINITY;
        for (int off = 32; off; off >>= 1) mv = fmaxf(mv, __shfl_xor(mv, off));
        float ev = (lane < NCLASS) ? __expf(logit - mv) : 0.f;
        float sum = ev;
        for (int off = 32; off; off >>= 1) sum += __shfl_xor(sum, off);
        if (lane < NCLASS)
            out[(size_t)node * NCLASS + lane] = logit - mv - logf(sum);
    }
}

// ---------------- launch ----------------

extern "C" void kernel_launch(void* const* d_in, const int* in_sizes, int n_in,
                              void* d_out, int out_size, void* d_ws, size_t ws_size,
                              hipStream_t stream) {
    const float* features = (const float*)d_in[0];
    const int*   erow     = (const int*)d_in[1];
    const int*   ecol     = (const int*)d_in[2];
    const float* eval_    = (const float*)d_in[3];
    const float* Wg       = (const float*)d_in[4];
    const float* att_w    = (const float*)d_in[5];
    const float* att_b    = (const float*)d_in[6];
    const float* fc_w     = (const float*)d_in[7];
    const float* fc_b     = (const float*)d_in[8];
    float*       out      = (float*)d_out;

    // workspace layout (float-size slots; ~135 MB total)
    float* hb  = (float*)d_ws;                 // 4*NF   : h1..h4
    float* tmp = hb + 4 * (size_t)NF;          // NF     : spmm result
    int2*  ev  = (int2*)(tmp + NF);            // E int2 : packed (col, val)
    int*   rp  = (int*)(ev + E);               // N+1 (+pad)
    int*   cnt = rp + (N + 4);                 // N      : histogram / cursor

    // CSR build
    hipMemsetAsync(cnt, 0, N * sizeof(int), stream);
    k_hist<<<(E + 255) / 256, 256, 0, stream>>>(erow, cnt);
    k_scan<<<1, 1024, 0, stream>>>(cnt, rp);
    k_scatter<<<(E + 255) / 256, 256, 0, stream>>>(erow, ecol, eval_, cnt, ev);

    // hops
    const float* hprev = features;
    for (int i = 0; i < NUM_HOPS; ++i) {
        k_spmm<<<(N * 64 + 255) / 256, 256, 0, stream>>>(rp, ev, hprev, tmp);
        k_gemm_relu<<<(N + GR - 1) / GR, 256, 0, stream>>>(tmp, Wg + (size_t)i * NHID * NHID,
                                                           hb + (size_t)i * NF);
        hprev = hb + (size_t)i * NF;
    }

    // fused attention + fc + log_softmax
    k_attn_final<<<(N + 3) / 4, 256, 0, stream>>>(features, hb, att_w, att_b, fc_w, fc_b, out);
}

// Round 4
// 623.524 us; speedup vs baseline: 2.2107x; 1.1243x over previous
//
#include <hip/hip_runtime.h>
#include <cmath>

#define N      50000
#define E      800000
#define NFEAT  128
#define NHID   128
#define NCLASS 40
#define NUM_HOPS 4
#define NF     (N * NHID)   // 6,400,000 floats per h buffer
#define GR     64           // GEMM rows per block
#define NB     ((N + 255) / 256)   // 196 scan blocks

// ---------------- CSR build ----------------

__global__ void k_hist(const int* __restrict__ row, int* __restrict__ cnt) {
    int e = blockIdx.x * blockDim.x + threadIdx.x;
    if (e < E) atomicAdd(&cnt[row[e]], 1);
}

// Phase 1: per-block (256 elems) reduction of cnt -> bsum[block]
__global__ void k_bsum(const int* __restrict__ cnt, int* __restrict__ bsum) {
    int t = threadIdx.x;
    int i = blockIdx.x * 256 + t;
    int v = (i < N) ? cnt[i] : 0;
    for (int off = 32; off; off >>= 1) v += __shfl_xor(v, off);
    __shared__ int ws[4];
    if ((t & 63) == 0) ws[t >> 6] = v;
    __syncthreads();
    if (t == 0) bsum[blockIdx.x] = ws[0] + ws[1] + ws[2] + ws[3];
}

// Phase 2: single small block scans bsum[0..NB-1] -> exclusive boff[0..NB-1]
__global__ void k_scanb(const int* __restrict__ bsum, int* __restrict__ boff) {
    __shared__ int ws[4];
    int t = threadIdx.x;
    int v = (t < NB) ? bsum[t] : 0;
    int lane = t & 63, w = t >> 6;
    int incl = v;
    for (int off = 1; off < 64; off <<= 1) {
        int u = __shfl_up(incl, off);
        if (lane >= off) incl += u;
    }
    if (lane == 63) ws[w] = incl;
    __syncthreads();
    int woff = 0;
    for (int k = 0; k < w; ++k) woff += ws[k];
    if (t < NB) boff[t] = incl - v + woff;
}

// Phase 3: in-block exclusive scan of cnt chunk + block offset -> rp; cnt becomes cursor
__global__ void k_expand(int* __restrict__ cnt, const int* __restrict__ boff,
                         int* __restrict__ rp) {
    __shared__ int ws[4];
    int t = threadIdx.x;
    int i = blockIdx.x * 256 + t;
    int c = (i < N) ? cnt[i] : 0;
    int lane = t & 63, w = t >> 6;
    int incl = c;
    for (int off = 1; off < 64; off <<= 1) {
        int u = __shfl_up(incl, off);
        if (lane >= off) incl += u;
    }
    if (lane == 63) ws[w] = incl;
    __syncthreads();
    int woff = 0;
    for (int k = 0; k < w; ++k) woff += ws[k];
    int r = boff[blockIdx.x] + incl - c + woff;   // exclusive prefix
    if (i < N) {
        rp[i]  = r;
        cnt[i] = r;           // scatter cursor
        if (i == N - 1) rp[N] = r + c;   // = E
    }
}

__global__ void k_scatter(const int* __restrict__ row, const int* __restrict__ col,
                          const float* __restrict__ val,
                          int* __restrict__ cur, int2* __restrict__ ev) {
    int e = blockIdx.x * blockDim.x + threadIdx.x;
    if (e < E) {
        int r = row[e];
        int p = atomicAdd(&cur[r], 1);
        ev[p] = make_int2(col[e], __float_as_int(val[e]));
    }
}

// ---------------- SpMM: y[row] = sum_j val_j * x[col_j]  (one wave per row) ----------------
// Edge-unrolled x8: 8 independent 512 B row-gathers in flight per wave (MLP).
// FMA chain preserves strict sequential edge order.

__global__ void k_spmm(const int* __restrict__ rp, const int2* __restrict__ ev,
                       const float* __restrict__ x, float* __restrict__ y) {
    int wid  = (blockIdx.x * blockDim.x + threadIdx.x) >> 6;   // global wave id = row
    if (wid >= N) return;
    int lane = threadIdx.x & 63;
    int beg = rp[wid], end = rp[wid + 1];
    float ax = 0.f, ay = 0.f;
    int j = beg;
    for (; j + 8 <= end; j += 8) {
        int2 e0 = ev[j],     e1 = ev[j + 1], e2 = ev[j + 2], e3 = ev[j + 3];
        int2 e4 = ev[j + 4], e5 = ev[j + 5], e6 = ev[j + 6], e7 = ev[j + 7];
        float2 x0 = ((const float2*)(x + (size_t)e0.x * NHID))[lane];
        float2 x1 = ((const float2*)(x + (size_t)e1.x * NHID))[lane];
        float2 x2 = ((const float2*)(x + (size_t)e2.x * NHID))[lane];
        float2 x3 = ((const float2*)(x + (size_t)e3.x * NHID))[lane];
        float2 x4 = ((const float2*)(x + (size_t)e4.x * NHID))[lane];
        float2 x5 = ((const float2*)(x + (size_t)e5.x * NHID))[lane];
        float2 x6 = ((const float2*)(x + (size_t)e6.x * NHID))[lane];
        float2 x7 = ((const float2*)(x + (size_t)e7.x * NHID))[lane];
        ax = fmaf(__int_as_float(e0.y), x0.x, ax); ay = fmaf(__int_as_float(e0.y), x0.y, ay);
        ax = fmaf(__int_as_float(e1.y), x1.x, ax); ay = fmaf(__int_as_float(e1.y), x1.y, ay);
        ax = fmaf(__int_as_float(e2.y), x2.x, ax); ay = fmaf(__int_as_float(e2.y), x2.y, ay);
        ax = fmaf(__int_as_float(e3.y), x3.x, ax); ay = fmaf(__int_as_float(e3.y), x3.y, ay);
        ax = fmaf(__int_as_float(e4.y), x4.x, ax); ay = fmaf(__int_as_float(e4.y), x4.y, ay);
        ax = fmaf(__int_as_float(e5.y), x5.x, ax); ay = fmaf(__int_as_float(e5.y), x5.y, ay);
        ax = fmaf(__int_as_float(e6.y), x6.x, ax); ay = fmaf(__int_as_float(e6.y), x6.y, ay);
        ax = fmaf(__int_as_float(e7.y), x7.x, ax); ay = fmaf(__int_as_float(e7.y), x7.y, ay);
    }
    for (; j < end; ++j) {
        int2 e = ev[j];
        const float2 xv = ((const float2*)(x + (size_t)e.x * NHID))[lane];
        float v = __int_as_float(e.y);
        ax = fmaf(v, xv.x, ax);
        ay = fmaf(v, xv.y, ay);
    }
    float2 o; o.x = ax; o.y = ay;
    ((float2*)(y + (size_t)wid * NHID))[lane] = o;
}

// ---------------- GEMM (128x128 W) + ReLU ----------------
// 64 rows/block, 256 threads, thread tile 8 rows x 4 cols (32 accumulators).
// x tile staged in LDS (32 KB); W streamed float4 with k+1 prefetch (L2-hot).

__global__ __launch_bounds__(256) void k_gemm_relu(const float* __restrict__ x,
                                                   const float* __restrict__ W,
                                                   float* __restrict__ y) {
    __shared__ float xl[GR * NHID];
    int t = threadIdx.x;
    int rowbase = blockIdx.x * GR;
    int nrows = N - rowbase; if (nrows > GR) nrows = GR;
    {
        float4* xl4 = (float4*)xl;
        const float4* xg4 = (const float4*)(x + (size_t)rowbase * NHID);
        int maxq = nrows * (NHID / 4);
#pragma unroll
        for (int i = 0; i < (GR * NHID / 4) / 256; ++i) {   // 8 iters
            int idx = i * 256 + t;
            if (idx < maxq) xl4[idx] = xg4[idx];
        }
    }
    __syncthreads();
    int cg = (t & 31) << 2;   // col base (4 cols)
    int rg = (t >> 5) << 3;   // row base (8 rows)
    float4 acc[8];
#pragma unroll
    for (int r = 0; r < 8; ++r) acc[r] = make_float4(0.f, 0.f, 0.f, 0.f);
    const float4* Wq = (const float4*)W;
    float4 w = Wq[cg >> 2];
    for (int k = 0; k < NHID; ++k) {
        float4 wn = (k + 1 < NHID) ? Wq[(k + 1) * (NHID / 4) + (cg >> 2)] : w;
#pragma unroll
        for (int r = 0; r < 8; ++r) {
            float xv = xl[(rg + r) * NHID + k];
            acc[r].x = fmaf(xv, w.x, acc[r].x);
            acc[r].y = fmaf(xv, w.y, acc[r].y);
            acc[r].z = fmaf(xv, w.z, acc[r].z);
            acc[r].w = fmaf(xv, w.w, acc[r].w);
        }
        w = wn;
    }
#pragma unroll
    for (int r = 0; r < 8; ++r) {
        int row = rowbase + rg + r;
        if (row < N) {
            float4 o;
            o.x = fmaxf(acc[r].x, 0.f);
            o.y = fmaxf(acc[r].y, 0.f);
            o.z = fmaxf(acc[r].z, 0.f);
            o.w = fmaxf(acc[r].w, 0.f);
            *(float4*)(y + (size_t)row * NHID + cg) = o;
        }
    }
}

// ---------------- Fused attention + output head (one wave per node) ----------------

__global__ void k_attn_final(const float* __restrict__ f, const float* __restrict__ hb,
                             const float* __restrict__ att_w, const float* __restrict__ att_b,
                             const float* __restrict__ fc_w, const float* __restrict__ fc_b,
                             float* __restrict__ out) {
    __shared__ float xs[4][NHID];
    int wslot = threadIdx.x >> 6;
    int node  = blockIdx.x * 4 + wslot;
    int lane  = threadIdx.x & 63;
    if (node < N) {
        const float2 whv = ((const float2*)att_w)[lane];
        const float2 wfv = ((const float2*)(att_w + NHID))[lane];
        const float2 fv  = ((const float2*)(f + (size_t)node * NFEAT))[lane];
        const float2 h0 = ((const float2*)(hb + 0 * (size_t)NF + (size_t)node * NHID))[lane];
        const float2 h1 = ((const float2*)(hb + 1 * (size_t)NF + (size_t)node * NHID))[lane];
        const float2 h2 = ((const float2*)(hb + 2 * (size_t)NF + (size_t)node * NHID))[lane];
        const float2 h3 = ((const float2*)(hb + 3 * (size_t)NF + (size_t)node * NHID))[lane];
        float s0 = h0.x * whv.x + h0.y * whv.y;
        float s1 = h1.x * whv.x + h1.y * whv.y;
        float s2 = h2.x * whv.x + h2.y * whv.y;
        float s3 = h3.x * whv.x + h3.y * whv.y;
        float s4 = fv.x * wfv.x + fv.y * wfv.y;
        for (int off = 32; off; off >>= 1) {
            s0 += __shfl_xor(s0, off);
            s1 += __shfl_xor(s1, off);
            s2 += __shfl_xor(s2, off);
            s3 += __shfl_xor(s3, off);
            s4 += __shfl_xor(s4, off);
        }
        float b = att_b[0];
        float g0 = 1.f / (1.f + __expf(-(s0 + s4 + b)));
        float g1 = 1.f / (1.f + __expf(-(s1 + s4 + b)));
        float g2 = 1.f / (1.f + __expf(-(s2 + s4 + b)));
        float g3 = 1.f / (1.f + __expf(-(s3 + s4 + b)));
        float m = fmaxf(fmaxf(g0, g1), fmaxf(g2, g3));
        float e0 = __expf(g0 - m), e1 = __expf(g1 - m), e2 = __expf(g2 - m), e3 = __expf(g3 - m);
        float inv = 1.f / (e0 + e1 + e2 + e3);
        float w0 = e0 * inv, w1 = e1 * inv, w2 = e2 * inv, w3 = e3 * inv;
        float ax = w0 * h0.x + w1 * h1.x + w2 * h2.x + w3 * h3.x;
        float ay = w0 * h0.y + w1 * h1.y + w2 * h2.y + w3 * h3.y;
        xs[wslot][2 * lane]     = ax;
        xs[wslot][2 * lane + 1] = ay;
    }
    __syncthreads();
    if (node < N) {
        float logit = 0.f;
        if (lane < NCLASS) {
            logit = fc_b[lane];
#pragma unroll 8
            for (int k = 0; k < NHID; ++k)
                logit = fmaf(xs[wslot][k], fc_w[k * NCLASS + lane], logit);
        }
        float mv = (lane < NCLASS) ? logit : -INFINITY;
        for (int off = 32; off; off >>= 1) mv = fmaxf(mv, __shfl_xor(mv, off));
        float ev = (lane < NCLASS) ? __expf(logit - mv) : 0.f;
        float sum = ev;
        for (int off = 32; off; off >>= 1) sum += __shfl_xor(sum, off);
        if (lane < NCLASS)
            out[(size_t)node * NCLASS + lane] = logit - mv - logf(sum);
    }
}

// ---------------- launch ----------------

extern "C" void kernel_launch(void* const* d_in, const int* in_sizes, int n_in,
                              void* d_out, int out_size, void* d_ws, size_t ws_size,
                              hipStream_t stream) {
    const float* features = (const float*)d_in[0];
    const int*   erow     = (const int*)d_in[1];
    const int*   ecol     = (const int*)d_in[2];
    const float* eval_    = (const float*)d_in[3];
    const float* Wg       = (const float*)d_in[4];
    const float* att_w    = (const float*)d_in[5];
    const float* att_b    = (const float*)d_in[6];
    const float* fc_w     = (const float*)d_in[7];
    const float* fc_b     = (const float*)d_in[8];
    float*       out      = (float*)d_out;

    // workspace layout (float-size slots; ~135 MB total)
    float* hb   = (float*)d_ws;                // 4*NF   : h1..h4
    float* tmp  = hb + 4 * (size_t)NF;         // NF     : spmm result
    int2*  ev   = (int2*)(tmp + NF);           // E int2 : packed (col, val)
    int*   rp   = (int*)(ev + E);              // N+1 (+pad)
    int*   cnt  = rp + (N + 4);                // N      : histogram / cursor
    int*   bsum = cnt + N;                     // NB     : block sums
    int*   boff = bsum + NB;                   // NB     : block offsets

    // CSR build
    hipMemsetAsync(cnt, 0, N * sizeof(int), stream);
    k_hist<<<(E + 255) / 256, 256, 0, stream>>>(erow, cnt);
    k_bsum<<<NB, 256, 0, stream>>>(cnt, bsum);
    k_scanb<<<1, 256, 0, stream>>>(bsum, boff);
    k_expand<<<NB, 256, 0, stream>>>(cnt, boff, rp);
    k_scatter<<<(E + 255) / 256, 256, 0, stream>>>(erow, ecol, eval_, cnt, ev);

    // hops
    const float* hprev = features;
    for (int i = 0; i < NUM_HOPS; ++i) {
        k_spmm<<<(N * 64 + 255) / 256, 256, 0, stream>>>(rp, ev, hprev, tmp);
        k_gemm_relu<<<(N + GR - 1) / GR, 256, 0, stream>>>(tmp, Wg + (size_t)i * NHID * NHID,
                                                           hb + (size_t)i * NF);
        hprev = hb + (size_t)i * NF;
    }

    // fused attention + fc + log_softmax
    k_attn_final<<<(N + 3) / 4, 256, 0, stream>>>(features, hb, att_w, att_b, fc_w, fc_b, out);
}